// Round 4
// baseline (751.706 us; speedup 1.0000x reference)
//
#include <hip/hip_runtime.h>
#include <stdint.h>

#define LVL 24
#define NN  8192
#define DIN 256
#define DD  128
#define BM  32       // nodes per tile; tile covers a 64-wide d-half (4 waves, 2 m-tiles each)
#define NBLK 512     // (NN/BM) * 2 d-halves == persistent grid size
#define CSW 66       // cs row stride (floats): 66 mod 32 = 2 -> conflict-free f32x4 writes

typedef __attribute__((ext_vector_type(8))) short bf16x8;
typedef __attribute__((ext_vector_type(4))) float f32x4;

__device__ __forceinline__ float b2f(unsigned short u) {
    union { unsigned int i; float f; } v; v.i = ((unsigned int)u) << 16; return v.f;
}
__device__ __forceinline__ unsigned short f2b(float f) {
    union { float f; unsigned int i; } v; v.f = f;
    unsigned int x = v.i;
    return (unsigned short)((x + 0x7fffu + ((x >> 16) & 1u)) >> 16);  // RNE
}
__device__ __forceinline__ float sig_(float x) { return 1.0f / (1.0f + __expf(-x)); }

__device__ __forceinline__ float ldf(const void* p, size_t i, int isf) {
    return isf ? ((const float*)p)[i] : b2f(((const unsigned short*)p)[i]);
}

// ---------------- dtype detector (unchanged) ----------------
__global__ void detect_kernel(const unsigned short* __restrict__ t, int* __restrict__ flag) {
    __shared__ int cnt;
    if (threadIdx.x == 0) cnt = 0;
    __syncthreads();
    int bad = 0;
    #pragma unroll
    for (int r = 0; r < 4; ++r) {
        unsigned short u = t[(threadIdx.x * 4 + r) * 2];
        int e = (u >> 7) & 255;
        bad += (e >= 136 || (e >= 1 && e <= 90)) ? 1 : 0;
    }
    atomicAdd(&cnt, bad);
    __syncthreads();
    if (threadIdx.x == 0) *flag = (cnt > 16) ? 1 : 0;
}

// ---------------- weight conversion into FRAGMENT-MAJOR packed layout ----------------
// Logical rows: [0,512)=W_w(f,i,u,o); [512,640)=U_f1; [640,768)=U_f2; [768,1152)=U_iuo.
// Packed element index: ((g*8+dt)*8 + kk)*512 + (q*16+m)*8 + j
//   where row = g*128 + dt*16 + m, col = kk*32 + q*8 + j.
// bid==1155 zeroes the global-barrier state (must precede fused_kernel each replay).
__global__ __launch_bounds__(256)
void convert_kernel(const void* Ww, const void* Wb, const void* Uf1, const void* Uf2,
                    const void* Uiuo, const void* hini, const void* cini,
                    unsigned short* __restrict__ wpack, float* __restrict__ bias,
                    unsigned short* __restrict__ hinit_b, float* __restrict__ cinit_f,
                    unsigned int* __restrict__ bar,
                    const int* __restrict__ flag) {
    const int isf = *flag;
    const int bid = blockIdx.x;
    const int t = threadIdx.x;
    if (bid < 1152) {
        const int row = bid, col = t;
        float v;
        if (row < 512)       v = ldf(Ww,   (size_t)row * DIN + col, isf);
        else if (row < 640)  v = ldf(Uf1,  (size_t)(row - 512) * DIN + col, isf);
        else if (row < 768)  v = ldf(Uf2,  (size_t)(row - 640) * DIN + col, isf);
        else                 v = ldf(Uiuo, (size_t)(row - 768) * DIN + col, isf);
        const int g  = row >> 7;
        const int wr = row & 127;
        const int dt = wr >> 4;
        const int mm = wr & 15;
        const int kk = col >> 5;
        const int q  = (col >> 3) & 3;
        const int j  = col & 7;
        const size_t pos = (size_t)((g * 8 + dt) * 8 + kk) * 512 + (q * 16 + mm) * 8 + j;
        wpack[pos] = f2b(v);
    } else if (bid == 1152) {
        bias[t] = ldf(Wb, t, isf);
    } else if (bid == 1153) {
        bias[256 + t] = ldf(Wb, 256 + t, isf);
    } else if (bid == 1154) {
        if (t < 128) hinit_b[t] = f2b(ldf(hini, t, isf));
        else if (t < 256) cinit_f[t - 128] = ldf(cini, t - 128, isf);
    } else {
        for (int i = t; i < 320; i += 256) bar[i] = 0u;   // 8 spread + master + gen (128B apart)
    }
}

// ---------------- shared tile helpers ----------------
__device__ __forceinline__ void stage_x_tile(unsigned short* __restrict__ xsbuf,
                                             const void* __restrict__ xbase,
                                             int level, int bm, int tid, int isf) {
    const int u0 = tid >> 4;          // 0..15
    const int r0 = tid & 15;
    #pragma unroll
    for (int du = 0; du < 2; ++du) {
        const int u = u0 + du * 16;   // octet of the 256-wide row
        const int kk = u >> 2, qq = u & 3;
        #pragma unroll
        for (int dr = 0; dr < 2; ++dr) {
            const int r = r0 + dr * 16;
            const size_t re = (size_t)level * NN * DIN + (size_t)(bm * BM + r) * DIN + u * 8;
            union { unsigned short us[8]; uint4 v; } t;
            if (isf) {
                const float4* xr = (const float4*)((const float*)xbase + re);
                float4 v0 = xr[0], v1 = xr[1];
                t.us[0] = f2b(v0.x); t.us[1] = f2b(v0.y); t.us[2] = f2b(v0.z); t.us[3] = f2b(v0.w);
                t.us[4] = f2b(v1.x); t.us[5] = f2b(v1.y); t.us[6] = f2b(v1.z); t.us[7] = f2b(v1.w);
            } else {
                t.v = *(const uint4*)((const unsigned short*)xbase + re);
            }
            *(uint4*)&xsbuf[kk * 1024 + qq * 256 + r * 8] = t.v;
        }
    }
}

// lean two-phase global barrier: spread arrivals (8 x 128B-apart counters, monotonic
// across levels -> no reset), master counter, generation flag. Release fence (L2 wb)
// before arrive; acquire fence (L2 inv) after observing the generation.
__device__ __forceinline__ void lean_barrier(unsigned int* __restrict__ bar, int lvl, int bid) {
    __syncthreads();                  // all block work drained to L2 (vmcnt0 before s_barrier)
    if (threadIdx.x == 0) {
        __builtin_amdgcn_fence(__ATOMIC_RELEASE, "agent");
        const int slot = bid & 7;
        unsigned int prev = __hip_atomic_fetch_add(&bar[slot * 32], 1u,
                                                   __ATOMIC_RELAXED, __HIP_MEMORY_SCOPE_AGENT);
        if (prev + 1u == (unsigned int)(64 * (lvl + 1))) {
            unsigned int mp = __hip_atomic_fetch_add(&bar[8 * 32], 1u,
                                                     __ATOMIC_RELAXED, __HIP_MEMORY_SCOPE_AGENT);
            if (mp + 1u == (unsigned int)(8 * (lvl + 1))) {
                __hip_atomic_store(&bar[9 * 32], (unsigned int)(lvl + 1),
                                   __ATOMIC_RELEASE, __HIP_MEMORY_SCOPE_AGENT);
            }
        }
        while (__hip_atomic_load(&bar[9 * 32], __ATOMIC_RELAXED,
                                 __HIP_MEMORY_SCOPE_AGENT) < (unsigned int)(lvl + 1))
            __builtin_amdgcn_s_sleep(8);
        __builtin_amdgcn_fence(__ATOMIC_ACQUIRE, "agent");
    }
    __syncthreads();
}

// ---------------- persistent all-levels kernel (lean barrier) ----------------
__global__ __launch_bounds__(256, 2)
void fused_kernel(const void* __restrict__ xbase,
                  const int* __restrict__ idxall,        // [L, NN, 2]
                  unsigned short* __restrict__ hb0,      // [NN, DD] bf16 ping
                  unsigned short* __restrict__ hb1,      // [NN, DD] bf16 pong
                  float* __restrict__ out,               // [2L, NN, DD]
                  const unsigned short* __restrict__ wpack,
                  const float* __restrict__ bias,
                  const unsigned short* __restrict__ hinit_b,
                  const float* __restrict__ cinit_f,
                  const int* __restrict__ flag,
                  unsigned int* __restrict__ bar) {
    __shared__ unsigned short xs[2][8192];   // 32 KB (double-buffered x tile)
    __shared__ unsigned short hs[8192];      // 16 KB
    __shared__ float cs[64 * CSW];           // 16.9 KB

    const int tid = threadIdx.x;
    const int isf = *flag;
    const int bid = blockIdx.x;              // 0..511
    const int bm  = bid & 255;
    const int yh  = bid >> 8;                // d-half

    // --- hoisted per-thread constants (persistent bonus) ---
    const int lane = tid & 63;
    const int wave = tid >> 6;
    const int m    = lane & 15;
    const int q    = lane >> 4;
    const int dt   = yh * 4 + wave;
    const int d    = yh * 64 + wave * 16 + m;
    const int dloc = wave * 16 + m;
    const unsigned short* wb = wpack + (size_t)dt * 4096 + (size_t)lane * 8;
    const float bfv = bias[d], biv = bias[128 + d], buv = bias[256 + d], bov = bias[384 + d];
    const float ci_init = cinit_f[d];

    // gather-phase roles (hoisted)
    const int gr  = tid & 31;                // node row in tile
    const int gsp = tid >> 5;                // 0..7
    const int gs    = gsp >> 2;              // child 0/1
    const int gpart = gsp & 3;               // 64B chunk

    stage_x_tile(xs[0], xbase, 0, bm, tid, isf);

    for (int l = 0; l < LVL; ++l) {
        const int first = (l == 0) ? 1 : 0;
        const int* __restrict__ idx = idxall + (size_t)l * NN * 2;
        const unsigned short* __restrict__ hprev = (l & 1) ? hb1 : hb0;
        unsigned short* __restrict__ hnew        = (l & 1) ? hb0 : hb1;
        const float* __restrict__ cprev = out + (size_t)(LVL + l - 1) * NN * DD; // first-guarded
        float* __restrict__ outh = out + (size_t)l * NN * DD;
        float* __restrict__ outc = out + (size_t)(LVL + l) * NN * DD;

        // ---- gather children h (full 128-d) and c (this d-half) ----
        {
            const int ai = idx[(bm * BM + gr) * 2 + gs];
            const int use_init = (first || ai < 0);

            const unsigned short* hsrc = use_init ? (hinit_b + gpart * 32)
                                                  : (hprev + (size_t)ai * DD + gpart * 32);
            const int kk = gs * 4 + gpart;
            #pragma unroll
            for (int qq = 0; qq < 4; ++qq)
                *(uint4*)&hs[kk * 1024 + qq * 256 + gr * 8] = ((const uint4*)hsrc)[qq];

            const float* csrc = use_init ? (cinit_f + yh * 64 + gpart * 16)
                                         : (cprev + (size_t)ai * DD + yh * 64 + gpart * 16);
            float* cdst = &cs[(gs * 32 + gr) * CSW + gpart * 16];
            #pragma unroll
            for (int qq = 0; qq < 4; ++qq)
                ((float4*)cdst)[qq] = ((const float4*)csrc)[qq];
        }
        __syncthreads();

        // ---- MFMA: 9 gates x 2 m-tiles, K=256 in 8 steps ----
        const unsigned short* __restrict__ xcur = xs[l & 1];
        f32x4 acc[9][2];
        #pragma unroll
        for (int g = 0; g < 9; ++g) { acc[g][0] = (f32x4)0.0f; acc[g][1] = (f32x4)0.0f; }

        #pragma unroll
        for (int kk = 0; kk < 8; ++kk) {
            const int xo = kk * 1024 + q * 256 + m * 8;
            bf16x8 a0 = *(const bf16x8*)&xcur[xo];
            bf16x8 a1 = *(const bf16x8*)&xcur[xo + 128];
            bf16x8 h0 = *(const bf16x8*)&hs[xo];
            bf16x8 h1 = *(const bf16x8*)&hs[xo + 128];
            #pragma unroll
            for (int g = 0; g < 4; ++g) {
                bf16x8 b = *(const bf16x8*)(wb + (size_t)g * 32768 + kk * 512);
                acc[g][0] = __builtin_amdgcn_mfma_f32_16x16x32_bf16(a0, b, acc[g][0], 0, 0, 0);
                acc[g][1] = __builtin_amdgcn_mfma_f32_16x16x32_bf16(a1, b, acc[g][1], 0, 0, 0);
            }
            #pragma unroll
            for (int g = 4; g < 9; ++g) {
                bf16x8 b = *(const bf16x8*)(wb + (size_t)g * 32768 + kk * 512);
                acc[g][0] = __builtin_amdgcn_mfma_f32_16x16x32_bf16(h0, b, acc[g][0], 0, 0, 0);
                acc[g][1] = __builtin_amdgcn_mfma_f32_16x16x32_bf16(h1, b, acc[g][1], 0, 0, 0);
            }
        }

        // ---- prefetch next level's x into the other LDS buffer (x is read-only) ----
        if (l + 1 < LVL)
            stage_x_tile(xs[(l + 1) & 1], xbase, l + 1, bm, tid, isf);

        // ---- pointwise LSTM ----
        #pragma unroll
        for (int mt = 0; mt < 2; ++mt) {
            #pragma unroll
            for (int j = 0; j < 4; ++j) {
                const int rr = mt * 16 + q * 4 + j;
                const int nd = bm * BM + rr;
                const float ca = cs[rr * CSW + dloc];
                const float cb = cs[(32 + rr) * CSW + dloc];
                const float fx = acc[0][mt][j] + bfv;
                const float ix = acc[1][mt][j] + biv;
                const float ux = acc[2][mt][j] + buv;
                const float ox = acc[3][mt][j] + bov;
                const float f1 = sig_(fx + acc[4][mt][j]);
                const float f2 = sig_(fx + acc[5][mt][j]);
                const float ig = sig_(ix + acc[6][mt][j]);
                const float ug = tanhf(ux + acc[7][mt][j]);
                const float og = sig_(ox + acc[8][mt][j]);
                const float nc = ig * ug + f1 * ca + f2 * cb;
                const float nh = og * tanhf(nc);
                const size_t o = (size_t)nd * DD + d;
                hnew[o] = f2b(nh);
                outh[o] = nh;
                outc[o] = nc;
            }
        }

        if (l + 1 < LVL) lean_barrier(bar, l, bid);
    }
}

// ---------------- fallback: per-level kernel (round-3 structure, cs stride fixed) ----------------
__global__ __launch_bounds__(256, 3)
void level_kernel(const void* __restrict__ xbase, int level,
                  const int* __restrict__ idx,
                  const unsigned short* __restrict__ hprev,
                  const float* __restrict__ cprev,
                  unsigned short* __restrict__ hnew,
                  float* __restrict__ outh,
                  float* __restrict__ outc,
                  const unsigned short* __restrict__ wpack,
                  const float* __restrict__ bias,
                  const unsigned short* __restrict__ hinit_b,
                  const float* __restrict__ cinit_f,
                  const int* __restrict__ flag,
                  int first) {
    __shared__ unsigned short xs[8192];
    __shared__ unsigned short hs[8192];
    __shared__ float cs[64 * CSW];

    const int tid = threadIdx.x;
    const int isf = *flag;
    const int bm  = blockIdx.x;
    const int yh  = blockIdx.y;

    stage_x_tile(xs, xbase, level, bm, tid, isf);
    {
        const int r  = tid & 31;
        const int sp = tid >> 5;
        const int s    = sp >> 2;
        const int part = sp & 3;
        const int ai = idx[(bm * BM + r) * 2 + s];
        const int use_init = (first || ai < 0);

        const unsigned short* hsrc = use_init ? (hinit_b + part * 32)
                                              : (hprev + (size_t)ai * DD + part * 32);
        const int kk = s * 4 + part;
        #pragma unroll
        for (int qq = 0; qq < 4; ++qq)
            *(uint4*)&hs[kk * 1024 + qq * 256 + r * 8] = ((const uint4*)hsrc)[qq];

        const float* csrc = use_init ? (cinit_f + yh * 64 + part * 16)
                                     : (cprev + (size_t)ai * DD + yh * 64 + part * 16);
        float* cdst = &cs[(s * 32 + r) * CSW + part * 16];
        #pragma unroll
        for (int qq = 0; qq < 4; ++qq)
            ((float4*)cdst)[qq] = ((const float4*)csrc)[qq];
    }
    __syncthreads();

    const int lane = tid & 63;
    const int wave = tid >> 6;
    const int m    = lane & 15;
    const int q    = lane >> 4;
    const int dt   = yh * 4 + wave;
    const int d    = yh * 64 + wave * 16 + m;
    const unsigned short* wb = wpack + (size_t)dt * 4096 + (size_t)lane * 8;

    f32x4 acc[9][2];
    #pragma unroll
    for (int g = 0; g < 9; ++g) { acc[g][0] = (f32x4)0.0f; acc[g][1] = (f32x4)0.0f; }

    #pragma unroll
    for (int kk = 0; kk < 8; ++kk) {
        const int xo = kk * 1024 + q * 256 + m * 8;
        bf16x8 a0 = *(const bf16x8*)&xs[xo];
        bf16x8 a1 = *(const bf16x8*)&xs[xo + 128];
        bf16x8 h0 = *(const bf16x8*)&hs[xo];
        bf16x8 h1 = *(const bf16x8*)&hs[xo + 128];
        #pragma unroll
        for (int g = 0; g < 4; ++g) {
            bf16x8 b = *(const bf16x8*)(wb + (size_t)g * 32768 + kk * 512);
            acc[g][0] = __builtin_amdgcn_mfma_f32_16x16x32_bf16(a0, b, acc[g][0], 0, 0, 0);
            acc[g][1] = __builtin_amdgcn_mfma_f32_16x16x32_bf16(a1, b, acc[g][1], 0, 0, 0);
        }
        #pragma unroll
        for (int g = 4; g < 9; ++g) {
            bf16x8 b = *(const bf16x8*)(wb + (size_t)g * 32768 + kk * 512);
            acc[g][0] = __builtin_amdgcn_mfma_f32_16x16x32_bf16(h0, b, acc[g][0], 0, 0, 0);
            acc[g][1] = __builtin_amdgcn_mfma_f32_16x16x32_bf16(h1, b, acc[g][1], 0, 0, 0);
        }
    }

    const float bfv = bias[d], biv = bias[128 + d], buv = bias[256 + d], bov = bias[384 + d];
    const int dloc = wave * 16 + m;
    #pragma unroll
    for (int mt = 0; mt < 2; ++mt) {
        #pragma unroll
        for (int j = 0; j < 4; ++j) {
            const int rr = mt * 16 + q * 4 + j;
            const int nd = bm * BM + rr;
            const float ca = cs[rr * CSW + dloc];
            const float cb = cs[(32 + rr) * CSW + dloc];
            const float fx = acc[0][mt][j] + bfv;
            const float ix = acc[1][mt][j] + biv;
            const float ux = acc[2][mt][j] + buv;
            const float ox = acc[3][mt][j] + bov;
            const float f1 = sig_(fx + acc[4][mt][j]);
            const float f2 = sig_(fx + acc[5][mt][j]);
            const float ig = sig_(ix + acc[6][mt][j]);
            const float ug = tanhf(ux + acc[7][mt][j]);
            const float og = sig_(ox + acc[8][mt][j]);
            const float nc = ig * ug + f1 * ca + f2 * cb;
            const float nh = og * tanhf(nc);
            const size_t o = (size_t)nd * DD + d;
            hnew[o] = f2b(nh);
            outh[o] = nh;
            outc[o] = nc;
        }
    }
}

extern "C" void kernel_launch(void* const* d_in, const int* in_sizes, int n_in,
                              void* d_out, int out_size, void* d_ws, size_t ws_size,
                              hipStream_t stream) {
    const void* tensor  = d_in[0];
    const int*  indices = (const int*)d_in[1];
    const void* h_init  = d_in[2];
    const void* c_init  = d_in[3];
    const void* Ww      = d_in[4];
    const void* Wb      = d_in[5];
    const void* Uf1     = d_in[6];
    const void* Uf2     = d_in[7];
    const void* Uiuo    = d_in[8];
    float* out = (float*)d_out;   // fp32: [h(L,N,D) | c(L,N,D)]

    char* wsb = (char*)d_ws;
    int* flag                = (int*)wsb;                               // @0
    unsigned short* wpack    = (unsigned short*)(wsb + 256);            // 589,824 B
    float* bias              = (float*)(wsb + 590336);                  // 2 KB
    unsigned short* hinit_b  = (unsigned short*)(wsb + 592640);         // 256 B
    float* cinit_f           = (float*)(wsb + 593152);                  // 512 B
    unsigned int* bar        = (unsigned int*)(wsb + 594176);           // 1280 B barrier state
    unsigned short* hb0      = (unsigned short*)(wsb + (1u << 20));             // 2 MB
    unsigned short* hb1      = (unsigned short*)(wsb + (1u << 20) + 2097152);   // 2 MB

    detect_kernel<<<1, 64, 0, stream>>>((const unsigned short*)tensor, flag);
    convert_kernel<<<1156, 256, 0, stream>>>(Ww, Wb, Uf1, Uf2, Uiuo, h_init, c_init,
                                             wpack, bias, hinit_b, cinit_f, bar, flag);

    static int nb = -1;
    if (nb < 0) {
        if (hipOccupancyMaxActiveBlocksPerMultiprocessor(&nb, fused_kernel, 256, 0)
            != hipSuccess) nb = 0;
    }

    if (nb >= 2) {
        // persistent path: 512 blocks == exactly 2/CU, all co-resident (cooperative launch)
        void* kargs[] = { (void*)&tensor, (void*)&indices, (void*)&hb0, (void*)&hb1,
                          (void*)&out, (void*)&wpack, (void*)&bias, (void*)&hinit_b,
                          (void*)&cinit_f, (void*)&flag, (void*)&bar };
        hipLaunchCooperativeKernel((const void*)fused_kernel, dim3(NBLK), dim3(256),
                                   kargs, 0, stream);
    } else {
        unsigned short* hp = hb0;
        unsigned short* hn = hb1;
        for (int l = 0; l < LVL; ++l) {
            const float* cprev = (l == 0) ? (const float*)out
                                          : (const float*)(out + (size_t)(LVL + l - 1) * NN * DD);
            level_kernel<<<dim3(NN / BM, 2), 256, 0, stream>>>(
                tensor, l,
                indices + (size_t)l * NN * 2,
                hp, cprev, hn,
                out + (size_t)l * NN * DD,
                out + (size_t)(LVL + l) * NN * DD,
                wpack, bias, hinit_b, cinit_f, flag, (l == 0) ? 1 : 0);
            unsigned short* th = hp; hp = hn; hn = th;
        }
    }
}